// Round 3
// baseline (25827.606 us; speedup 1.0000x reference)
//
#include <hip/hip_runtime.h>

// LiquidNeuralNetwork: B=512, S=1024, IN=16, HID=64, OUT=1, N_SUB=4 (RK4).
// TWO independent batch chains per wave (lane i = hidden unit i of both):
// chain B's VALU work hides chain A's LDS broadcast round-trip latency.
// 256 blocks x 64 threads = 1 wave/CU. Weights shared across the 2 chains.
// dt is constant (linspace): step 0 has dt=0 -> h stays 0, out[0]=b_out.

constexpr int HID  = 64;
constexpr int INF  = 16;
constexpr int SLEN = 1024;

__device__ __forceinline__ float fast_tanh(float x) {
    // tanh(x) = 1 - 2/(e^{2x}+1); exact limits at +/-inf, no clamp needed.
    float e = __builtin_amdgcn_exp2f(x * 2.8853900817779268f); // 2*log2(e)
    float r = __builtin_amdgcn_rcpf(e + 1.0f);
    return fmaf(-2.0f, r, 1.0f);
}

__global__ __launch_bounds__(64, 1) void lnn_scan2_kernel(
    const float* __restrict__ x,
    const float* __restrict__ W_in,
    const float* __restrict__ b_in,
    const float* __restrict__ W_hh,
    const float* __restrict__ W_ih,
    const float* __restrict__ bias,
    const float* __restrict__ tau,
    const float* __restrict__ W_out,
    const float* __restrict__ b_out,
    float* __restrict__ out)
{
    const int lane = threadIdx.x;        // hidden index
    const int bA   = blockIdx.x * 2;     // chain A batch index
    const int bB   = bA + 1;             // chain B batch index

    __shared__ float thA_s[HID];         // one wave per block -> wave-private
    __shared__ float thB_s[HID];

    // --- one-time setup (shared by both chains) ---
    float w[HID];                        // my W_hh row
    {
        const float4* w4 = (const float4*)(W_hh + lane * HID);
        #pragma unroll
        for (int q = 0; q < HID / 4; ++q) {
            float4 v = w4[q];
            w[4*q+0] = v.x; w[4*q+1] = v.y; w[4*q+2] = v.z; w[4*q+3] = v.w;
        }
    }
    float Wc[INF];                       // (W_ih @ W_in) row for my unit
    #pragma unroll
    for (int k = 0; k < INF; ++k) Wc[k] = 0.0f;
    float bcomb = 0.0f;
    for (int j = 0; j < HID; ++j) {
        float wij = W_ih[lane * HID + j];
        bcomb = fmaf(wij, b_in[j], bcomb);
        #pragma unroll
        for (int k = 0; k < INF; ++k) Wc[k] = fmaf(wij, W_in[j * INF + k], Wc[k]);
    }
    const float cbase = bcomb + bias[lane];
    const float rtau  = 1.0f / tau[lane];
    const float wo    = W_out[lane];
    const float bo    = b_out[0];

    float cA = 0.0f, cB = 0.0f;

    // dual ode_f: both chains evaluated together; compiler interleaves so
    // each chain's LDS round-trip hides behind the other's VALU work.
    auto odef2 = [&](float yA, float yB, float& rA, float& rB) {
        float tA = fast_tanh(yA);
        float tB = fast_tanh(yB);
        thA_s[lane] = tA;                // intra-wave: no barrier needed
        thB_s[lane] = tB;
        float a0 = 0.f, a1 = 0.f, a2 = 0.f, a3 = 0.f;
        float b0 = 0.f, b1 = 0.f, b2 = 0.f, b3 = 0.f;
        const float4* A4 = (const float4*)thA_s;
        const float4* B4 = (const float4*)thB_s;
        #pragma unroll
        for (int q = 0; q < HID / 4; ++q) {
            float4 ta = A4[q];
            float4 tb = B4[q];
            a0 = fmaf(w[4*q+0], ta.x, a0);
            a1 = fmaf(w[4*q+1], ta.y, a1);
            a2 = fmaf(w[4*q+2], ta.z, a2);
            a3 = fmaf(w[4*q+3], ta.w, a3);
            b0 = fmaf(w[4*q+0], tb.x, b0);
            b1 = fmaf(w[4*q+1], tb.y, b1);
            b2 = fmaf(w[4*q+2], tb.z, b2);
            b3 = fmaf(w[4*q+3], tb.w, b3);
        }
        rA = ((a0 + a1) + (a2 + a3) + (cA - yA)) * rtau;
        rB = ((b0 + b1) + (b2 + b3) + (cB - yB)) * rtau;
    };

    float hA = 0.0f, hB = 0.0f;
    // dt = 1/1023 for all steps s>=1 (s=0: dt=0 -> h unchanged; out[0]=bo)
    const float hsub = (1.0f / 1023.0f) * 0.25f;
    const float h6   = hsub * (1.0f / 6.0f);

    const float4* xrA = (const float4*)(x + (size_t)bA * SLEN * INF);
    const float4* xrB = (const float4*)(x + (size_t)bB * SLEN * INF);
    float* orA = out + (size_t)bA * SLEN;
    float* orB = out + (size_t)bB * SLEN;

    if (lane == 0) { orA[0] = bo; orB[0] = bo; }  // h=0 after step 0

    // prefetch x for s=1
    float4 xa0 = xrA[4], xa1 = xrA[5], xa2 = xrA[6], xa3 = xrA[7];
    float4 xb0 = xrB[4], xb1 = xrB[5], xb2 = xrB[6], xb3 = xrB[7];

    for (int s = 1; s < SLEN; ++s) {
        // c per chain from prefetched regs (parallel FMA trees)
        {
            float cA1 = fmaf(xa0.x, Wc[0], fmaf(xa0.y, Wc[1],
                        fmaf(xa0.z, Wc[2], fmaf(xa0.w, Wc[3], cbase))));
            float cA2 = fmaf(xa1.x, Wc[4], fmaf(xa1.y, Wc[5],
                        fmaf(xa1.z, Wc[6], xa1.w * Wc[7])));
            float cA3 = fmaf(xa2.x, Wc[8], fmaf(xa2.y, Wc[9],
                        fmaf(xa2.z, Wc[10], xa2.w * Wc[11])));
            float cA4 = fmaf(xa3.x, Wc[12], fmaf(xa3.y, Wc[13],
                        fmaf(xa3.z, Wc[14], xa3.w * Wc[15])));
            cA = (cA1 + cA2) + (cA3 + cA4);
            float cB1 = fmaf(xb0.x, Wc[0], fmaf(xb0.y, Wc[1],
                        fmaf(xb0.z, Wc[2], fmaf(xb0.w, Wc[3], cbase))));
            float cB2 = fmaf(xb1.x, Wc[4], fmaf(xb1.y, Wc[5],
                        fmaf(xb1.z, Wc[6], xb1.w * Wc[7])));
            float cB3 = fmaf(xb2.x, Wc[8], fmaf(xb2.y, Wc[9],
                        fmaf(xb2.z, Wc[10], xb2.w * Wc[11])));
            float cB4 = fmaf(xb3.x, Wc[12], fmaf(xb3.y, Wc[13],
                        fmaf(xb3.z, Wc[14], xb3.w * Wc[15])));
            cB = (cB1 + cB2) + (cB3 + cB4);
        }
        // prefetch next step's x (hidden behind the 16 evals below)
        {
            int sn = (s < SLEN - 1) ? (s + 1) : (SLEN - 1);
            xa0 = xrA[sn*4+0]; xa1 = xrA[sn*4+1];
            xa2 = xrA[sn*4+2]; xa3 = xrA[sn*4+3];
            xb0 = xrB[sn*4+0]; xb1 = xrB[sn*4+1];
            xb2 = xrB[sn*4+2]; xb3 = xrB[sn*4+3];
        }

        #pragma unroll
        for (int sub = 0; sub < 4; ++sub) {
            float k1A, k1B, k2A, k2B, k3A, k3B, k4A, k4B;
            odef2(hA, hB, k1A, k1B);
            odef2(fmaf(0.5f * hsub, k1A, hA), fmaf(0.5f * hsub, k1B, hB), k2A, k2B);
            odef2(fmaf(0.5f * hsub, k2A, hA), fmaf(0.5f * hsub, k2B, hB), k3A, k3B);
            odef2(fmaf(hsub, k3A, hA), fmaf(hsub, k3B, hB), k4A, k4B);
            hA = fmaf(h6, fmaf(2.0f, k2A + k3A, k1A + k4A), hA);
            hB = fmaf(h6, fmaf(2.0f, k2B + k3B, k1B + k4B), hB);
        }

        // out[s] = tanh(h) . W_out + b_out, 64-lane butterfly (both chains
        // interleaved; only 1/16 of eval frequency)
        float vA = fast_tanh(hA) * wo;
        float vB = fast_tanh(hB) * wo;
        #pragma unroll
        for (int m = 32; m > 0; m >>= 1) {
            vA += __shfl_xor(vA, m, 64);
            vB += __shfl_xor(vB, m, 64);
        }
        if (lane == 0) { orA[s] = vA + bo; orB[s] = vB + bo; }
    }
}

extern "C" void kernel_launch(void* const* d_in, const int* in_sizes, int n_in,
                              void* d_out, int out_size, void* d_ws, size_t ws_size,
                              hipStream_t stream) {
    const float* x     = (const float*)d_in[0];
    const float* W_in  = (const float*)d_in[1];
    const float* b_in  = (const float*)d_in[2];
    const float* W_hh  = (const float*)d_in[3];
    const float* W_ih  = (const float*)d_in[4];
    const float* bias  = (const float*)d_in[5];
    const float* tau   = (const float*)d_in[6];
    const float* W_out = (const float*)d_in[7];
    const float* b_out = (const float*)d_in[8];
    float* out = (float*)d_out;

    lnn_scan2_kernel<<<256, 64, 0, stream>>>(x, W_in, b_in, W_hh, W_ih, bias,
                                             tau, W_out, b_out, out);
}

// Round 5
// 8460.915 us; speedup vs baseline: 3.0526x; 3.0526x over previous
//
#include <hip/hip_runtime.h>

// LiquidNeuralNetwork: B=512, S=1024, IN=16, HID=64, OUT=1, N_SUB=4 (RK4).
// TWO independent batch chains per wave (lane i = hidden unit i of both),
// with the tanh broadcast packed as half2 {tA,tB}: ONE ds_write_b32 and 16
// shared ds_read_b128 per dual-eval. v_fma_mix consumes f16 halves with fp32
// accumulate. 256 blocks x 64 threads. Weights shared across the 2 chains.
// dt is constant (linspace): step 0 has dt=0 -> h stays 0, out[0]=b_out.

constexpr int HID  = 64;
constexpr int INF  = 16;
constexpr int SLEN = 1024;

typedef __fp16 h2_t __attribute__((ext_vector_type(2)));  // cvt_pkrtz return type

__device__ __forceinline__ float fast_tanh(float x) {
    // tanh(x) = 1 - 2/(e^{2x}+1); exact limits at +/-inf, no clamp needed.
    float e = __builtin_amdgcn_exp2f(x * 2.8853900817779268f); // 2*log2(e)
    float r = __builtin_amdgcn_rcpf(e + 1.0f);
    return fmaf(-2.0f, r, 1.0f);
}

__global__ __launch_bounds__(64, 1) void lnn_scan2h_kernel(
    const float* __restrict__ x,
    const float* __restrict__ W_in,
    const float* __restrict__ b_in,
    const float* __restrict__ W_hh,
    const float* __restrict__ W_ih,
    const float* __restrict__ bias,
    const float* __restrict__ tau,
    const float* __restrict__ W_out,
    const float* __restrict__ b_out,
    float* __restrict__ out)
{
    const int lane = threadIdx.x;        // hidden index
    const int bA   = blockIdx.x * 2;     // chain A batch index
    const int bB   = bA + 1;             // chain B batch index

    __shared__ unsigned th_s[HID];       // half2{tA,tB} per hidden unit, 256B

    // --- one-time setup (shared by both chains) ---
    float w[HID];                        // my W_hh row
    {
        const float4* w4 = (const float4*)(W_hh + lane * HID);
        #pragma unroll
        for (int q = 0; q < HID / 4; ++q) {
            float4 v = w4[q];
            w[4*q+0] = v.x; w[4*q+1] = v.y; w[4*q+2] = v.z; w[4*q+3] = v.w;
        }
    }
    float Wc[INF];                       // (W_ih @ W_in) row for my unit
    #pragma unroll
    for (int k = 0; k < INF; ++k) Wc[k] = 0.0f;
    float bcomb = 0.0f;
    for (int j = 0; j < HID; ++j) {
        float wij = W_ih[lane * HID + j];
        bcomb = fmaf(wij, b_in[j], bcomb);
        #pragma unroll
        for (int k = 0; k < INF; ++k) Wc[k] = fmaf(wij, W_in[j * INF + k], Wc[k]);
    }
    const float cbase = bcomb + bias[lane];
    const float rtau  = 1.0f / tau[lane];
    const float wo    = W_out[lane];
    const float bo    = b_out[0];

    float cA = 0.0f, cB = 0.0f;

    // dual ode_f via packed half2 broadcast
    auto odef2 = [&](float yA, float yB, float& rA, float& rB) {
        float tA = fast_tanh(yA);
        float tB = fast_tanh(yB);
        h2_t pk = __builtin_amdgcn_cvt_pkrtz(tA, tB);
        th_s[lane] = __builtin_bit_cast(unsigned, pk);   // one ds_write_b32
        float a0 = 0.f, a1 = 0.f, a2 = 0.f, a3 = 0.f;
        float b0 = 0.f, b1 = 0.f, b2 = 0.f, b3 = 0.f;
        const uint4* t4 = (const uint4*)th_s;
        #pragma unroll
        for (int q = 0; q < HID / 4; ++q) {              // 16x ds_read_b128
            uint4 r = t4[q];
            h2_t h0 = __builtin_bit_cast(h2_t, r.x);
            h2_t h1 = __builtin_bit_cast(h2_t, r.y);
            h2_t h2v = __builtin_bit_cast(h2_t, r.z);
            h2_t h3 = __builtin_bit_cast(h2_t, r.w);
            a0 = fmaf((float)h0[0], w[4*q+0], a0);
            b0 = fmaf((float)h0[1], w[4*q+0], b0);
            a1 = fmaf((float)h1[0], w[4*q+1], a1);
            b1 = fmaf((float)h1[1], w[4*q+1], b1);
            a2 = fmaf((float)h2v[0], w[4*q+2], a2);
            b2 = fmaf((float)h2v[1], w[4*q+2], b2);
            a3 = fmaf((float)h3[0], w[4*q+3], a3);
            b3 = fmaf((float)h3[1], w[4*q+3], b3);
        }
        rA = ((a0 + a1) + (a2 + a3) + (cA - yA)) * rtau;
        rB = ((b0 + b1) + (b2 + b3) + (cB - yB)) * rtau;
    };

    float hA = 0.0f, hB = 0.0f;
    // dt = 1/1023 for all steps s>=1 (s=0: dt=0 -> h unchanged; out[0]=bo)
    const float hsub = (1.0f / 1023.0f) * 0.25f;
    const float h6   = hsub * (1.0f / 6.0f);

    const float4* xrA = (const float4*)(x + (size_t)bA * SLEN * INF);
    const float4* xrB = (const float4*)(x + (size_t)bB * SLEN * INF);
    float* orA = out + (size_t)bA * SLEN;
    float* orB = out + (size_t)bB * SLEN;

    if (lane == 0) { orA[0] = bo; orB[0] = bo; }  // h=0 after step 0

    // prefetch x for s=1
    float4 xa0 = xrA[4], xa1 = xrA[5], xa2 = xrA[6], xa3 = xrA[7];
    float4 xb0 = xrB[4], xb1 = xrB[5], xb2 = xrB[6], xb3 = xrB[7];

    for (int s = 1; s < SLEN; ++s) {
        // c per chain from prefetched regs (parallel FMA trees)
        {
            float cA1 = fmaf(xa0.x, Wc[0], fmaf(xa0.y, Wc[1],
                        fmaf(xa0.z, Wc[2], fmaf(xa0.w, Wc[3], cbase))));
            float cA2 = fmaf(xa1.x, Wc[4], fmaf(xa1.y, Wc[5],
                        fmaf(xa1.z, Wc[6], xa1.w * Wc[7])));
            float cA3 = fmaf(xa2.x, Wc[8], fmaf(xa2.y, Wc[9],
                        fmaf(xa2.z, Wc[10], xa2.w * Wc[11])));
            float cA4 = fmaf(xa3.x, Wc[12], fmaf(xa3.y, Wc[13],
                        fmaf(xa3.z, Wc[14], xa3.w * Wc[15])));
            cA = (cA1 + cA2) + (cA3 + cA4);
            float cB1 = fmaf(xb0.x, Wc[0], fmaf(xb0.y, Wc[1],
                        fmaf(xb0.z, Wc[2], fmaf(xb0.w, Wc[3], cbase))));
            float cB2 = fmaf(xb1.x, Wc[4], fmaf(xb1.y, Wc[5],
                        fmaf(xb1.z, Wc[6], xb1.w * Wc[7])));
            float cB3 = fmaf(xb2.x, Wc[8], fmaf(xb2.y, Wc[9],
                        fmaf(xb2.z, Wc[10], xb2.w * Wc[11])));
            float cB4 = fmaf(xb3.x, Wc[12], fmaf(xb3.y, Wc[13],
                        fmaf(xb3.z, Wc[14], xb3.w * Wc[15])));
            cB = (cB1 + cB2) + (cB3 + cB4);
        }
        // prefetch next step's x (hidden behind the 16 evals below)
        {
            int sn = (s < SLEN - 1) ? (s + 1) : (SLEN - 1);
            xa0 = xrA[sn*4+0]; xa1 = xrA[sn*4+1];
            xa2 = xrA[sn*4+2]; xa3 = xrA[sn*4+3];
            xb0 = xrB[sn*4+0]; xb1 = xrB[sn*4+1];
            xb2 = xrB[sn*4+2]; xb3 = xrB[sn*4+3];
        }

        // keep scheduler scope bounded (spill guard): don't unroll substeps
        #pragma unroll 1
        for (int sub = 0; sub < 4; ++sub) {
            float k1A, k1B, k2A, k2B, k3A, k3B, k4A, k4B;
            odef2(hA, hB, k1A, k1B);
            odef2(fmaf(0.5f * hsub, k1A, hA), fmaf(0.5f * hsub, k1B, hB), k2A, k2B);
            odef2(fmaf(0.5f * hsub, k2A, hA), fmaf(0.5f * hsub, k2B, hB), k3A, k3B);
            odef2(fmaf(hsub, k3A, hA), fmaf(hsub, k3B, hB), k4A, k4B);
            hA = fmaf(h6, fmaf(2.0f, k2A + k3A, k1A + k4A), hA);
            hB = fmaf(h6, fmaf(2.0f, k2B + k3B, k1B + k4B), hB);
        }

        // out[s] = tanh(h) . W_out + b_out, 64-lane butterfly (1/16 of evals)
        float vA = fast_tanh(hA) * wo;
        float vB = fast_tanh(hB) * wo;
        #pragma unroll
        for (int m = 32; m > 0; m >>= 1) {
            vA += __shfl_xor(vA, m, 64);
            vB += __shfl_xor(vB, m, 64);
        }
        if (lane == 0) { orA[s] = vA + bo; orB[s] = vB + bo; }
    }
}

extern "C" void kernel_launch(void* const* d_in, const int* in_sizes, int n_in,
                              void* d_out, int out_size, void* d_ws, size_t ws_size,
                              hipStream_t stream) {
    const float* x     = (const float*)d_in[0];
    const float* W_in  = (const float*)d_in[1];
    const float* b_in  = (const float*)d_in[2];
    const float* W_hh  = (const float*)d_in[3];
    const float* W_ih  = (const float*)d_in[4];
    const float* bias  = (const float*)d_in[5];
    const float* tau   = (const float*)d_in[6];
    const float* W_out = (const float*)d_in[7];
    const float* b_out = (const float*)d_in[8];
    float* out = (float*)d_out;

    lnn_scan2h_kernel<<<256, 64, 0, stream>>>(x, W_in, b_in, W_hh, W_ih, bias,
                                              tau, W_out, b_out, out);
}

// Round 6
// 5707.664 us; speedup vs baseline: 4.5251x; 1.4824x over previous
//
#include <hip/hip_runtime.h>

// LiquidNeuralNetwork: B=512, S=1024, IN=16, HID=64, OUT=1, N_SUB=4 (RK4).
// One wave per batch element (512 blocks x 64 thr = 2 waves/CU; the HW
// scheduler overlaps the two independent waves' LDS latency -- round 5
// showed merging chains into one wave serializes them instead).
// tanh broadcast stored as f16: 64 x 2B = 128B -> ONE ds_write_b16 + EIGHT
// ds_read_b128 per eval (vs 16 fp32 reads). v_fma_mix consumes f16 with
// fp32 accumulate; 8 accumulator chains keep FMA depth at 8.
// dt is constant (linspace): step 0 has dt=0 -> h stays 0, out[0]=b_out.

constexpr int HID  = 64;
constexpr int INF  = 16;
constexpr int SLEN = 1024;

typedef __fp16 h2_t __attribute__((ext_vector_type(2)));

__device__ __forceinline__ float fast_tanh(float x) {
    // tanh(x) = 1 - 2/(e^{2x}+1); exact limits at +/-inf, no clamp needed.
    float e = __builtin_amdgcn_exp2f(x * 2.8853900817779268f); // 2*log2(e)
    float r = __builtin_amdgcn_rcpf(e + 1.0f);
    return fmaf(-2.0f, r, 1.0f);
}

__global__ __launch_bounds__(64, 1) void lnn_scanh_kernel(
    const float* __restrict__ x,
    const float* __restrict__ W_in,
    const float* __restrict__ b_in,
    const float* __restrict__ W_hh,
    const float* __restrict__ W_ih,
    const float* __restrict__ bias,
    const float* __restrict__ tau,
    const float* __restrict__ W_out,
    const float* __restrict__ b_out,
    float* __restrict__ out)
{
    const int lane = threadIdx.x;        // hidden index
    const int b    = blockIdx.x;         // batch index

    __shared__ __fp16 th_s[HID];         // f16 tanh vector, 128 B, wave-private

    // --- one-time setup ---
    float w[HID];                        // my W_hh row (fp32)
    {
        const float4* w4 = (const float4*)(W_hh + lane * HID);
        #pragma unroll
        for (int q = 0; q < HID / 4; ++q) {
            float4 v = w4[q];
            w[4*q+0] = v.x; w[4*q+1] = v.y; w[4*q+2] = v.z; w[4*q+3] = v.w;
        }
    }
    float Wc[INF];                       // (W_ih @ W_in) row for my unit
    #pragma unroll
    for (int k = 0; k < INF; ++k) Wc[k] = 0.0f;
    float bcomb = 0.0f;
    for (int j = 0; j < HID; ++j) {
        float wij = W_ih[lane * HID + j];
        bcomb = fmaf(wij, b_in[j], bcomb);
        #pragma unroll
        for (int k = 0; k < INF; ++k) Wc[k] = fmaf(wij, W_in[j * INF + k], Wc[k]);
    }
    const float cbase = bcomb + bias[lane];
    const float rtau  = 1.0f / tau[lane];
    const float wo    = W_out[lane];
    const float bo    = b_out[0];

    float c_step = 0.0f;

    // ode_f(y) = (matvec(tanh(y)) + c - y) * rtau, f16 broadcast
    auto odef = [&](float y) -> float {
        float t = fast_tanh(y);
        th_s[lane] = (__fp16)t;              // one ds_write_b16 (no barrier:
                                             // intra-wave, in-order DS pipe)
        float a0=0.f,a1=0.f,a2=0.f,a3=0.f,a4=0.f,a5=0.f,a6=0.f,a7=0.f;
        const uint4* t4 = (const uint4*)th_s;
        #pragma unroll
        for (int q = 0; q < 8; ++q) {        // 8x ds_read_b128 (16 halfs each)
            uint4 r = t4[q];
            h2_t p0 = __builtin_bit_cast(h2_t, r.x);
            h2_t p1 = __builtin_bit_cast(h2_t, r.y);
            h2_t p2 = __builtin_bit_cast(h2_t, r.z);
            h2_t p3 = __builtin_bit_cast(h2_t, r.w);
            a0 = fmaf((float)p0[0], w[8*q+0], a0);
            a1 = fmaf((float)p0[1], w[8*q+1], a1);
            a2 = fmaf((float)p1[0], w[8*q+2], a2);
            a3 = fmaf((float)p1[1], w[8*q+3], a3);
            a4 = fmaf((float)p2[0], w[8*q+4], a4);
            a5 = fmaf((float)p2[1], w[8*q+5], a5);
            a6 = fmaf((float)p3[0], w[8*q+6], a6);
            a7 = fmaf((float)p3[1], w[8*q+7], a7);
        }
        float s = ((a0 + a1) + (a2 + a3)) + ((a4 + a5) + (a6 + a7));
        return (s + c_step - y) * rtau;
    };

    float h = 0.0f;
    // dt = 1/1023 for all steps s>=1 (s=0: dt=0 -> h unchanged; out[0]=bo)
    const float hsub = (1.0f / 1023.0f) * 0.25f;
    const float h6   = hsub * (1.0f / 6.0f);

    const float4* xrow = (const float4*)(x + (size_t)b * SLEN * INF);
    float* orow = out + (size_t)b * SLEN;

    if (lane == 0) orow[0] = bo;             // h=0 after step 0

    // prefetch x for s=1
    float4 xp0 = xrow[4], xp1 = xrow[5], xp2 = xrow[6], xp3 = xrow[7];

    for (int s = 1; s < SLEN; ++s) {
        // c for this step from prefetched regs (4 parallel FMA trees)
        {
            float cA = fmaf(xp0.x, Wc[0], fmaf(xp0.y, Wc[1],
                       fmaf(xp0.z, Wc[2], fmaf(xp0.w, Wc[3], cbase))));
            float cB = fmaf(xp1.x, Wc[4], fmaf(xp1.y, Wc[5],
                       fmaf(xp1.z, Wc[6], xp1.w * Wc[7])));
            float cC = fmaf(xp2.x, Wc[8], fmaf(xp2.y, Wc[9],
                       fmaf(xp2.z, Wc[10], xp2.w * Wc[11])));
            float cD = fmaf(xp3.x, Wc[12], fmaf(xp3.y, Wc[13],
                       fmaf(xp3.z, Wc[14], xp3.w * Wc[15])));
            c_step = (cA + cB) + (cC + cD);
        }
        // prefetch next step's x (hidden behind the 16 evals below)
        {
            int sn = (s < SLEN - 1) ? (s + 1) : (SLEN - 1);
            xp0 = xrow[sn*4+0]; xp1 = xrow[sn*4+1];
            xp2 = xrow[sn*4+2]; xp3 = xrow[sn*4+3];
        }

        #pragma unroll
        for (int sub = 0; sub < 4; ++sub) {
            float k1 = odef(h);
            float k2 = odef(fmaf(0.5f * hsub, k1, h));
            float k3 = odef(fmaf(0.5f * hsub, k2, h));
            float k4 = odef(fmaf(hsub, k3, h));
            h = fmaf(h6, fmaf(2.0f, k2 + k3, k1 + k4), h);
        }

        // out[s] = tanh(h) . W_out + b_out, 64-lane butterfly (1/16 of evals)
        float v = fast_tanh(h) * wo;
        #pragma unroll
        for (int m = 32; m > 0; m >>= 1) v += __shfl_xor(v, m, 64);
        if (lane == 0) orow[s] = v + bo;
    }
}

extern "C" void kernel_launch(void* const* d_in, const int* in_sizes, int n_in,
                              void* d_out, int out_size, void* d_ws, size_t ws_size,
                              hipStream_t stream) {
    const float* x     = (const float*)d_in[0];
    const float* W_in  = (const float*)d_in[1];
    const float* b_in  = (const float*)d_in[2];
    const float* W_hh  = (const float*)d_in[3];
    const float* W_ih  = (const float*)d_in[4];
    const float* bias  = (const float*)d_in[5];
    const float* tau   = (const float*)d_in[6];
    const float* W_out = (const float*)d_in[7];
    const float* b_out = (const float*)d_in[8];
    float* out = (float*)d_out;

    lnn_scanh_kernel<<<512, 64, 0, stream>>>(x, W_in, b_in, W_hh, W_ih, bias,
                                             tau, W_out, b_out, out);
}

// Round 7
// 4824.144 us; speedup vs baseline: 5.3538x; 1.1831x over previous
//
#include <hip/hip_runtime.h>

// LiquidNeuralNetwork: B=512, S=1024, IN=16, HID=64, OUT=1, N_SUB=4 (RK4).
// Wall time = 16368 sequential ode_f evals x per-eval latency, so the only
// levers are shortening the dependent chain and amortizing the LDS
// write->read stall. This version: TWO chains per wave with SEPARATE f16
// LDS buffers (round 5's shared packed buffer serialized the chains), inner
// dot via v_dot2_f32_f16 (32 ops / 64 MACs, fp32 accumulate, no stray
// cvts), f16-packed weights. One lgkm stall per eval-PAIR.
// 256 blocks x 64 threads. dt constant (linspace); step 0: dt=0 -> out=b_out.

constexpr int HID  = 64;
constexpr int INF  = 16;
constexpr int SLEN = 1024;

typedef __fp16 h2_t __attribute__((ext_vector_type(2)));

__device__ __forceinline__ float fast_tanh(float x) {
    // tanh(x) = 1 - 2/(e^{2x}+1); exact limits at +/-inf, no clamp needed.
    float e = __builtin_amdgcn_exp2f(x * 2.8853900817779268f); // 2*log2(e)
    float r = __builtin_amdgcn_rcpf(e + 1.0f);
    return fmaf(-2.0f, r, 1.0f);
}

__global__ __launch_bounds__(64, 1) void lnn_dual_kernel(
    const float* __restrict__ x,
    const float* __restrict__ W_in,
    const float* __restrict__ b_in,
    const float* __restrict__ W_hh,
    const float* __restrict__ W_ih,
    const float* __restrict__ bias,
    const float* __restrict__ tau,
    const float* __restrict__ W_out,
    const float* __restrict__ b_out,
    float* __restrict__ out)
{
    const int lane = threadIdx.x;        // hidden index
    const int bA   = blockIdx.x * 2;     // chain A batch index
    const int bB   = bA + 1;             // chain B batch index

    __shared__ __fp16 tA_s[HID];         // 128 B, chain A broadcast
    __shared__ __fp16 tB_s[HID];         // 128 B, chain B broadcast

    // --- one-time setup (shared weights) ---
    h2_t wh[HID / 2];                    // my W_hh row, f16-packed pairs
    {
        const float4* w4 = (const float4*)(W_hh + lane * HID);
        #pragma unroll
        for (int q = 0; q < HID / 4; ++q) {
            float4 v = w4[q];
            wh[2*q+0] = __builtin_amdgcn_cvt_pkrtz(v.x, v.y);
            wh[2*q+1] = __builtin_amdgcn_cvt_pkrtz(v.z, v.w);
        }
    }
    float Wc[INF];                       // (W_ih @ W_in) row for my unit
    #pragma unroll
    for (int k = 0; k < INF; ++k) Wc[k] = 0.0f;
    float bcomb = 0.0f;
    for (int j = 0; j < HID; ++j) {
        float wij = W_ih[lane * HID + j];
        bcomb = fmaf(wij, b_in[j], bcomb);
        #pragma unroll
        for (int k = 0; k < INF; ++k) Wc[k] = fmaf(wij, W_in[j * INF + k], Wc[k]);
    }
    const float cbase = bcomb + bias[lane];
    const float rtau  = 1.0f / tau[lane];
    const float wo    = W_out[lane];
    const float bo    = b_out[0];

    float cA = 0.0f, cB = 0.0f;

    // dual ode_f: separate tanh->write->read->dot chains; compiler
    // interleaves so chain B's dot fills chain A's LDS stall (one lgkm
    // stall per pair).
    auto odef2 = [&](float yA, float yB, float& rA, float& rB) {
        float thA = fast_tanh(yA);
        tA_s[lane] = (__fp16)thA;            // ds_write_b16, chain A
        float thB = fast_tanh(yB);
        tB_s[lane] = (__fp16)thB;            // ds_write_b16, chain B
        float a0 = 0.f, a1 = 0.f, a2 = 0.f, a3 = 0.f;
        float b0 = 0.f, b1 = 0.f, b2 = 0.f, b3 = 0.f;
        const uint4* A4 = (const uint4*)tA_s;
        const uint4* B4 = (const uint4*)tB_s;
        #pragma unroll
        for (int q = 0; q < 8; ++q) {        // 8x ds_read_b128 chain A
            uint4 r = A4[q];
            a0 = __builtin_amdgcn_fdot2(__builtin_bit_cast(h2_t, r.x), wh[4*q+0], a0, false);
            a1 = __builtin_amdgcn_fdot2(__builtin_bit_cast(h2_t, r.y), wh[4*q+1], a1, false);
            a2 = __builtin_amdgcn_fdot2(__builtin_bit_cast(h2_t, r.z), wh[4*q+2], a2, false);
            a3 = __builtin_amdgcn_fdot2(__builtin_bit_cast(h2_t, r.w), wh[4*q+3], a3, false);
        }
        #pragma unroll
        for (int q = 0; q < 8; ++q) {        // 8x ds_read_b128 chain B
            uint4 r = B4[q];
            b0 = __builtin_amdgcn_fdot2(__builtin_bit_cast(h2_t, r.x), wh[4*q+0], b0, false);
            b1 = __builtin_amdgcn_fdot2(__builtin_bit_cast(h2_t, r.y), wh[4*q+1], b1, false);
            b2 = __builtin_amdgcn_fdot2(__builtin_bit_cast(h2_t, r.z), wh[4*q+2], b2, false);
            b3 = __builtin_amdgcn_fdot2(__builtin_bit_cast(h2_t, r.w), wh[4*q+3], b3, false);
        }
        rA = ((a0 + a1) + (a2 + a3) + (cA - yA)) * rtau;
        rB = ((b0 + b1) + (b2 + b3) + (cB - yB)) * rtau;
    };

    float hA = 0.0f, hB = 0.0f;
    // dt = 1/1023 for all steps s>=1 (s=0: dt=0 -> h unchanged; out[0]=bo)
    const float hsub  = (1.0f / 1023.0f) * 0.25f;
    const float hsubh = 0.5f * hsub;
    const float h6    = hsub * (1.0f / 6.0f);

    const float4* xrA = (const float4*)(x + (size_t)bA * SLEN * INF);
    const float4* xrB = (const float4*)(x + (size_t)bB * SLEN * INF);
    float* orA = out + (size_t)bA * SLEN;
    float* orB = out + (size_t)bB * SLEN;

    if (lane == 0) { orA[0] = bo; orB[0] = bo; }   // h=0 after step 0

    // prefetch x for s=1
    float4 xa0 = xrA[4], xa1 = xrA[5], xa2 = xrA[6], xa3 = xrA[7];
    float4 xb0 = xrB[4], xb1 = xrB[5], xb2 = xrB[6], xb3 = xrB[7];

    for (int s = 1; s < SLEN; ++s) {
        // c per chain from prefetched regs (parallel FMA trees)
        {
            float c1 = fmaf(xa0.x, Wc[0], fmaf(xa0.y, Wc[1],
                       fmaf(xa0.z, Wc[2], fmaf(xa0.w, Wc[3], cbase))));
            float c2 = fmaf(xa1.x, Wc[4], fmaf(xa1.y, Wc[5],
                       fmaf(xa1.z, Wc[6], xa1.w * Wc[7])));
            float c3 = fmaf(xa2.x, Wc[8], fmaf(xa2.y, Wc[9],
                       fmaf(xa2.z, Wc[10], xa2.w * Wc[11])));
            float c4 = fmaf(xa3.x, Wc[12], fmaf(xa3.y, Wc[13],
                       fmaf(xa3.z, Wc[14], xa3.w * Wc[15])));
            cA = (c1 + c2) + (c3 + c4);
            float d1 = fmaf(xb0.x, Wc[0], fmaf(xb0.y, Wc[1],
                       fmaf(xb0.z, Wc[2], fmaf(xb0.w, Wc[3], cbase))));
            float d2 = fmaf(xb1.x, Wc[4], fmaf(xb1.y, Wc[5],
                       fmaf(xb1.z, Wc[6], xb1.w * Wc[7])));
            float d3 = fmaf(xb2.x, Wc[8], fmaf(xb2.y, Wc[9],
                       fmaf(xb2.z, Wc[10], xb2.w * Wc[11])));
            float d4 = fmaf(xb3.x, Wc[12], fmaf(xb3.y, Wc[13],
                       fmaf(xb3.z, Wc[14], xb3.w * Wc[15])));
            cB = (d1 + d2) + (d3 + d4);
        }
        // prefetch next step's x (hidden behind the 16 dual-evals below)
        {
            int sn = (s < SLEN - 1) ? (s + 1) : (SLEN - 1);
            xa0 = xrA[sn*4+0]; xa1 = xrA[sn*4+1];
            xa2 = xrA[sn*4+2]; xa3 = xrA[sn*4+3];
            xb0 = xrB[sn*4+0]; xb1 = xrB[sn*4+1];
            xb2 = xrB[sn*4+2]; xb3 = xrB[sn*4+3];
        }

        // spill guard: bound scheduler scope, don't unroll substeps
        #pragma unroll 1
        for (int sub = 0; sub < 4; ++sub) {
            float k1A, k1B, k2A, k2B, k3A, k3B, k4A, k4B;
            odef2(hA, hB, k1A, k1B);
            odef2(fmaf(hsubh, k1A, hA), fmaf(hsubh, k1B, hB), k2A, k2B);
            odef2(fmaf(hsubh, k2A, hA), fmaf(hsubh, k2B, hB), k3A, k3B);
            odef2(fmaf(hsub, k3A, hA), fmaf(hsub, k3B, hB), k4A, k4B);
            hA = fmaf(h6, fmaf(2.0f, k2A + k3A, k1A + k4A), hA);
            hB = fmaf(h6, fmaf(2.0f, k2B + k3B, k1B + k4B), hB);
        }

        // out[s] = tanh(h) . W_out + b_out, 64-lane butterfly (1/16 of evals)
        float vA = fast_tanh(hA) * wo;
        float vB = fast_tanh(hB) * wo;
        #pragma unroll
        for (int m = 32; m > 0; m >>= 1) {
            vA += __shfl_xor(vA, m, 64);
            vB += __shfl_xor(vB, m, 64);
        }
        if (lane == 0) { orA[s] = vA + bo; orB[s] = vB + bo; }
    }
}

extern "C" void kernel_launch(void* const* d_in, const int* in_sizes, int n_in,
                              void* d_out, int out_size, void* d_ws, size_t ws_size,
                              hipStream_t stream) {
    const float* x     = (const float*)d_in[0];
    const float* W_in  = (const float*)d_in[1];
    const float* b_in  = (const float*)d_in[2];
    const float* W_hh  = (const float*)d_in[3];
    const float* W_ih  = (const float*)d_in[4];
    const float* bias  = (const float*)d_in[5];
    const float* tau   = (const float*)d_in[6];
    const float* W_out = (const float*)d_in[7];
    const float* b_out = (const float*)d_in[8];
    float* out = (float*)d_out;

    lnn_dual_kernel<<<256, 64, 0, stream>>>(x, W_in, b_in, W_hh, W_ih, bias,
                                            tau, W_out, b_out, out);
}

// Round 8
// 3106.902 us; speedup vs baseline: 8.3130x; 1.5527x over previous
//
#include <hip/hip_runtime.h>

// LiquidNeuralNetwork: B=512, S=1024, IN=16, HID=64, OUT=1, N_SUB=4 (RK4).
// Wall = 16368 x T(one wave advances its chain(s) by one eval). Waves are
// fully parallel, so minimize single-chain T: G=1 chain per wave (512 waves,
// 2/CU on separate SIMDs). fdot2 (v_dot2_f32_f16) inner product over an f16
// broadcast (1 ds_write_b16 + 8 ds_read_b128), acc0 seeded with (c - y),
// output dot fused into next step's first eval (no shuffle butterfly).
// dt constant (linspace); step 0 has dt=0 -> h stays 0, out[0]=b_out.

constexpr int HID  = 64;
constexpr int INF  = 16;
constexpr int SLEN = 1024;

typedef __fp16 h2_t __attribute__((ext_vector_type(2)));

__device__ __forceinline__ float fast_tanh(float x) {
    // tanh(x) = 1 - 2/(e^{2x}+1); exact limits at +/-inf, no clamp needed.
    float e = __builtin_amdgcn_exp2f(x * 2.8853900817779268f); // 2*log2(e)
    float r = __builtin_amdgcn_rcpf(e + 1.0f);
    return fmaf(-2.0f, r, 1.0f);
}

__global__ __launch_bounds__(64, 1) void lnn_single_kernel(
    const float* __restrict__ x,
    const float* __restrict__ W_in,
    const float* __restrict__ b_in,
    const float* __restrict__ W_hh,
    const float* __restrict__ W_ih,
    const float* __restrict__ bias,
    const float* __restrict__ tau,
    const float* __restrict__ W_out,
    const float* __restrict__ b_out,
    float* __restrict__ out)
{
    const int lane = threadIdx.x;        // hidden index
    const int b    = blockIdx.x;         // batch index

    __shared__ __fp16 th_s[HID];         // 128 B f16 broadcast, wave-private

    // --- one-time setup ---
    h2_t wh[HID / 2];                    // my W_hh row, f16-packed pairs
    {
        const float4* w4 = (const float4*)(W_hh + lane * HID);
        #pragma unroll
        for (int q = 0; q < HID / 4; ++q) {
            float4 v = w4[q];
            wh[2*q+0] = __builtin_amdgcn_cvt_pkrtz(v.x, v.y);
            wh[2*q+1] = __builtin_amdgcn_cvt_pkrtz(v.z, v.w);
        }
    }
    h2_t wov[HID / 2];                   // W_out row (replicated), f16 pairs
    {
        const float4* o4 = (const float4*)(W_out);
        #pragma unroll
        for (int q = 0; q < HID / 4; ++q) {
            float4 v = o4[q];
            wov[2*q+0] = __builtin_amdgcn_cvt_pkrtz(v.x, v.y);
            wov[2*q+1] = __builtin_amdgcn_cvt_pkrtz(v.z, v.w);
        }
    }
    float Wc[INF];                       // (W_ih @ W_in) row for my unit
    #pragma unroll
    for (int k = 0; k < INF; ++k) Wc[k] = 0.0f;
    float bcomb = 0.0f;
    for (int j = 0; j < HID; ++j) {
        float wij = W_ih[lane * HID + j];
        bcomb = fmaf(wij, b_in[j], bcomb);
        #pragma unroll
        for (int k = 0; k < INF; ++k) Wc[k] = fmaf(wij, W_in[j * INF + k], Wc[k]);
    }
    const float cbase = bcomb + bias[lane];
    const float rtau  = 1.0f / tau[lane];
    const float bo    = b_out[0];

    float c_step = 0.0f;

    // ode_f(y) = (dot(w, tanh_bcast) + c - y) * rtau ; acc0 seeded with c-y
    auto odef = [&](float y) -> float {
        float cmy = c_step - y;              // off critical path (|| tanh)
        float t = fast_tanh(y);
        th_s[lane] = (__fp16)t;              // ds_write_b16, intra-wave
        float a0 = cmy, a1 = 0.f, a2 = 0.f, a3 = 0.f;
        const uint4* t4 = (const uint4*)th_s;
        #pragma unroll
        for (int q = 0; q < 8; ++q) {        // 8x ds_read_b128
            uint4 r = t4[q];
            a0 = __builtin_amdgcn_fdot2(__builtin_bit_cast(h2_t, r.x), wh[4*q+0], a0, false);
            a1 = __builtin_amdgcn_fdot2(__builtin_bit_cast(h2_t, r.y), wh[4*q+1], a1, false);
            a2 = __builtin_amdgcn_fdot2(__builtin_bit_cast(h2_t, r.z), wh[4*q+2], a2, false);
            a3 = __builtin_amdgcn_fdot2(__builtin_bit_cast(h2_t, r.w), wh[4*q+3], a3, false);
        }
        return (((a0 + a1) + (a2 + a3))) * rtau;
    };

    // same, but also emits os = wov . tanh_bcast (previous step's output)
    auto odef_out = [&](float y, float& os) -> float {
        float cmy = c_step - y;
        float t = fast_tanh(y);
        th_s[lane] = (__fp16)t;
        float a0 = cmy, a1 = 0.f, a2 = 0.f, a3 = 0.f;
        float o0 = 0.f, o1 = 0.f, o2 = 0.f, o3 = 0.f;
        const uint4* t4 = (const uint4*)th_s;
        #pragma unroll
        for (int q = 0; q < 8; ++q) {        // same 8 reads feed both dots
            uint4 r = t4[q];
            h2_t px = __builtin_bit_cast(h2_t, r.x);
            h2_t py = __builtin_bit_cast(h2_t, r.y);
            h2_t pz = __builtin_bit_cast(h2_t, r.z);
            h2_t pw = __builtin_bit_cast(h2_t, r.w);
            a0 = __builtin_amdgcn_fdot2(px, wh[4*q+0], a0, false);
            a1 = __builtin_amdgcn_fdot2(py, wh[4*q+1], a1, false);
            a2 = __builtin_amdgcn_fdot2(pz, wh[4*q+2], a2, false);
            a3 = __builtin_amdgcn_fdot2(pw, wh[4*q+3], a3, false);
            o0 = __builtin_amdgcn_fdot2(px, wov[4*q+0], o0, false);
            o1 = __builtin_amdgcn_fdot2(py, wov[4*q+1], o1, false);
            o2 = __builtin_amdgcn_fdot2(pz, wov[4*q+2], o2, false);
            o3 = __builtin_amdgcn_fdot2(pw, wov[4*q+3], o3, false);
        }
        os = (o0 + o1) + (o2 + o3);
        return (((a0 + a1) + (a2 + a3))) * rtau;
    };

    float h = 0.0f;
    // dt = 1/1023 for all steps s>=1 (s=0: dt=0 -> h unchanged; out[0]=bo)
    const float hsub  = (1.0f / 1023.0f) * 0.25f;
    const float hsubh = 0.5f * hsub;
    const float h6    = hsub * (1.0f / 6.0f);

    const float4* xrow = (const float4*)(x + (size_t)b * SLEN * INF);
    float* orow = out + (size_t)b * SLEN;

    if (lane == 0) orow[0] = bo;             // h=0 after step 0

    // prefetch x for s=1
    float4 xp0 = xrow[4], xp1 = xrow[5], xp2 = xrow[6], xp3 = xrow[7];

    for (int s = 1; s < SLEN; ++s) {
        // c for this step from prefetched regs (4 parallel FMA trees)
        {
            float cA = fmaf(xp0.x, Wc[0], fmaf(xp0.y, Wc[1],
                       fmaf(xp0.z, Wc[2], fmaf(xp0.w, Wc[3], cbase))));
            float cB = fmaf(xp1.x, Wc[4], fmaf(xp1.y, Wc[5],
                       fmaf(xp1.z, Wc[6], xp1.w * Wc[7])));
            float cC = fmaf(xp2.x, Wc[8], fmaf(xp2.y, Wc[9],
                       fmaf(xp2.z, Wc[10], xp2.w * Wc[11])));
            float cD = fmaf(xp3.x, Wc[12], fmaf(xp3.y, Wc[13],
                       fmaf(xp3.z, Wc[14], xp3.w * Wc[15])));
            c_step = (cA + cB) + (cC + cD);
        }
        // prefetch next step's x (hidden behind the 16 evals below)
        {
            int sn = (s < SLEN - 1) ? (s + 1) : (SLEN - 1);
            xp0 = xrow[sn*4+0]; xp1 = xrow[sn*4+1];
            xp2 = xrow[sn*4+2]; xp3 = xrow[sn*4+3];
        }

        // substep 0: first eval also yields previous step's output
        {
            float os;
            float k1 = odef_out(h, os);
            if (lane == 0) orow[s - 1] = os + bo;
            float k2 = odef(fmaf(hsubh, k1, h));
            float k3 = odef(fmaf(hsubh, k2, h));
            float k4 = odef(fmaf(hsub, k3, h));
            h = fmaf(h6, fmaf(2.0f, k2 + k3, k1 + k4), h);
        }
        #pragma unroll
        for (int sub = 1; sub < 4; ++sub) {
            float k1 = odef(h);
            float k2 = odef(fmaf(hsubh, k1, h));
            float k3 = odef(fmaf(hsubh, k2, h));
            float k4 = odef(fmaf(hsub, k3, h));
            h = fmaf(h6, fmaf(2.0f, k2 + k3, k1 + k4), h);
        }
    }

    // epilogue: out[1023] = wov . tanh(h_final) + bo
    {
        float t = fast_tanh(h);
        th_s[lane] = (__fp16)t;
        float o0 = 0.f, o1 = 0.f, o2 = 0.f, o3 = 0.f;
        const uint4* t4 = (const uint4*)th_s;
        #pragma unroll
        for (int q = 0; q < 8; ++q) {
            uint4 r = t4[q];
            o0 = __builtin_amdgcn_fdot2(__builtin_bit_cast(h2_t, r.x), wov[4*q+0], o0, false);
            o1 = __builtin_amdgcn_fdot2(__builtin_bit_cast(h2_t, r.y), wov[4*q+1], o1, false);
            o2 = __builtin_amdgcn_fdot2(__builtin_bit_cast(h2_t, r.z), wov[4*q+2], o2, false);
            o3 = __builtin_amdgcn_fdot2(__builtin_bit_cast(h2_t, r.w), wov[4*q+3], o3, false);
        }
        if (lane == 0) orow[SLEN - 1] = (o0 + o1) + (o2 + o3) + bo;
    }
}

extern "C" void kernel_launch(void* const* d_in, const int* in_sizes, int n_in,
                              void* d_out, int out_size, void* d_ws, size_t ws_size,
                              hipStream_t stream) {
    const float* x     = (const float*)d_in[0];
    const float* W_in  = (const float*)d_in[1];
    const float* b_in  = (const float*)d_in[2];
    const float* W_hh  = (const float*)d_in[3];
    const float* W_ih  = (const float*)d_in[4];
    const float* bias  = (const float*)d_in[5];
    const float* tau   = (const float*)d_in[6];
    const float* W_out = (const float*)d_in[7];
    const float* b_out = (const float*)d_in[8];
    float* out = (float*)d_out;

    lnn_single_kernel<<<512, 64, 0, stream>>>(x, W_in, b_in, W_hh, W_ih, bias,
                                              tau, W_out, b_out, out);
}